// Round 3
// baseline (94.694 us; speedup 1.0000x reference)
//
#include <hip/hip_runtime.h>
#include <math.h>

#define NSTATE  256   // n_dist_support
#define NC      128   // data columns
#define CENTER  128   // reference_center
#define NITERS  33
#define NSHIFTS 129   // NSTATE - NC + 1
#define NSTEPS  6
#define PAD     4     // max |interval step|
#define LOG1EM38 (-87.4982335f)   // ln(1e-38), the reference's underflow clamp

__device__ __forceinline__ float wave_reduce_sum(float v) {
    #pragma unroll
    for (int off = 32; off > 0; off >>= 1) v += __shfl_down(v, off, 64);
    return v;
}
__device__ __forceinline__ float wave_reduce_min(float v) {
    #pragma unroll
    for (int off = 32; off > 0; off >>= 1) v = fminf(v, __shfl_down(v, off, 64));
    return v;
}

// One block per data row. 256 threads: one per diffusion state.
__global__ __launch_bounds__(256)
void tonal_diffusion_kernel(const float* __restrict__ data,
                            const float* __restrict__ logw,
                            float* __restrict__ out)
{
    const int row  = blockIdx.x;
    const int tid  = threadIdx.x;
    const int lane = tid & 63, wid = tid >> 6;
    const int steps[NSTEPS] = {1, -1, -3, 3, 4, -4};

    __shared__ float runA[NSTATE + 2 * PAD];   // zero-padded: no bounds checks
    __shared__ float runB[NSTATE + 2 * PAD];
    __shared__ float licd[NSTATE];             // log(raw acc)  (scale cancels in q)
    __shared__ float dsh [NC];                 // sanitized data (0 where isclose(0))
    __shared__ float P   [NSTATE];             // inclusive prefix of raw acc
    __shared__ float Zlog[NSHIFTS];            // log of raw slice sums
    __shared__ float wsum[4];
    __shared__ float red4[4];

    // --- per-row weights: w = exp(lw), rate = sum, p = w/rate (wave-uniform)
    float p[NSTEPS];
    float rate = 0.f;
    {
        const float* lw = logw + row * NSTEPS;
        #pragma unroll
        for (int i = 0; i < NSTEPS; ++i) { p[i] = expf(lw[i]); rate += p[i]; }
        const float inv = 1.0f / rate;
        #pragma unroll
        for (int i = 0; i < NSTEPS; ++i) p[i] *= inv;
    }

    // --- init buffers (+ zero pads; pads are never written again)
    runA[tid + PAD] = (tid == CENTER) ? 1.0f : 0.0f;
    if (tid < PAD) {
        runA[tid] = 0.f;              runB[tid] = 0.f;
        runA[NSTATE + PAD + tid] = 0.f; runB[NSTATE + PAD + tid] = 0.f;
    }

    // --- data load + plogp partial (overlaps with diffusion; red4 read later)
    float pl = 0.f;
    if (tid < NC) {
        const float dv = data[row * NC + tid];
        const bool nz = dv > 1e-8f;               // isclose(data, 0) atol
        pl = nz ? dv * logf(dv) : 0.f;
        dsh[tid] = nz ? dv : 0.f;                 // sanitized: excluded cols -> 0
    }
    {
        float v = wave_reduce_sum(pl);
        if (lane == 0) red4[wid] = v;
    }

    // --- Poisson-weighted Markov diffusion; pmf via recurrence (no lgamma)
    float accR = 0.f;                // acc for state `tid` stays in a register
    float sp = expf(-rate);          // Poisson pmf(0)
    float* cur = runA;
    float* nxt = runB;
    for (int n = 0; n < NITERS; ++n) {
        __syncthreads();             // cur[] fully written by previous iteration
        accR += sp * cur[tid + PAD];
        float rn = 0.f;
        #pragma unroll
        for (int i = 0; i < NSTEPS; ++i)
            rn += p[i] * cur[tid + PAD - steps[i]];   // pads supply zeros
        nxt[tid + PAD] = rn;
        sp = sp * rate / (float)(n + 1);              // pmf(n+1)
        float* t = cur; cur = nxt; nxt = t;
    }

    // --- licd + block-wide inclusive prefix sum of raw acc (shuffle scan)
    licd[tid] = logf(accR);          // logf(0) -> -inf, clamped in matching
    float v = accR;
    #pragma unroll
    for (int off = 1; off < 64; off <<= 1) {
        const float u = __shfl_up(v, off, 64);
        if (lane >= off) v += u;
    }
    if (lane == 63) wsum[wid] = v;
    __syncthreads();                                   // B1: wsum, red4, licd, dsh
    const float plogp_sum = red4[0] + red4[1] + red4[2] + red4[3];
    float base = 0.f;
    if (wid > 0) base += wsum[0];
    if (wid > 1) base += wsum[1];
    if (wid > 2) base += wsum[2];
    P[tid] = v + base;
    __syncthreads();                                   // B2: P visible
    if (tid < NSHIFTS) {
        const float Zs = P[tid + NC - 1] - (tid ? P[tid - 1] : 0.f);
        Zlog[tid] = logf(Zs);
    }
    __syncthreads();                                   // B3: Zlog visible

    // --- match: min over 129 shifts of DKL(data || normalized icd slice)
    // log q = licd[s+c] - logZ_s ; per-term clamp max(., ln 1e-38) == reference.
    // 2 threads per shift (64 cols each), combined via shfl_xor(1).
    float best = INFINITY;
    for (int w = tid; w < 2 * NSHIFTS; w += 256) {     // trip2: lanes 0,1 -> s=128
        const int s = w >> 1;
        const int cbase = (w & 1) << 6;
        const float logZ = Zlog[s];
        float part = 0.f;
        #pragma unroll 16
        for (int cc = 0; cc < 64; ++cc) {
            const int c = cbase + cc;
            part += dsh[c] * fmaxf(licd[s + c] - logZ, LOG1EM38);
        }
        part += __shfl_xor(part, 1, 64);               // partner lane w^1, same wave
        if ((w & 1) == 0) best = fminf(best, plogp_sum - part);
    }
    {
        float m = wave_reduce_min(best);
        if (lane == 0) red4[wid] = m;                  // red4 reads done pre-B2
    }
    __syncthreads();                                   // B4
    if (tid == 0)
        out[row] = fminf(fminf(red4[0], red4[1]), fminf(red4[2], red4[3]));
}

extern "C" void kernel_launch(void* const* d_in, const int* in_sizes, int n_in,
                              void* d_out, int out_size, void* d_ws, size_t ws_size,
                              hipStream_t stream)
{
    const float* data = (const float*)d_in[0];   // [n, 128] f32
    const float* logw = (const float*)d_in[1];   // [n, 6]   f32
    float* out = (float*)d_out;                  // [n]      f32
    const int n_rows = in_sizes[0] / NC;
    tonal_diffusion_kernel<<<n_rows, 256, 0, stream>>>(data, logw, out);
}

// Round 4
// 77.787 us; speedup vs baseline: 1.2173x; 1.2173x over previous
//
#include <hip/hip_runtime.h>
#include <math.h>

#define NC      128   // data columns
#define NSTATE  256   // n_dist_support
#define NITERS  33
#define NSTEPS  6
#define RPB     4     // rows (= independent waves) per block
#define CL2     (-126.22347f)          // log2(1e-38): reference underflow clamp
#define LN2     (0.6931471805599453f)

// One WAVE per data row; 4 independent waves per block; NO __syncthreads anywhere.
// Diffusion states live in registers: state 4*lane+j  (j=0..3), neighbors via shfl.
__global__ __launch_bounds__(256)
void tonal_diffusion_kernel(const float* __restrict__ data,
                            const float* __restrict__ logw,
                            float* __restrict__ out, int n_rows)
{
    const int wid  = threadIdx.x >> 6;
    const int lane = threadIdx.x & 63;
    const int row  = blockIdx.x * RPB + wid;
    if (row >= n_rows) return;          // safe: no barriers in this kernel

    __shared__ float licd_s[RPB][NSTATE];
    __shared__ float P_s   [RPB][NSTATE];
    __shared__ float dsh_s [RPB][NC];
    float* __restrict__ licd = licd_s[wid];   // log2(raw acc)
    float* __restrict__ P    = P_s[wid];      // inclusive prefix of raw acc
    float* __restrict__ dsh  = dsh_s[wid];    // sanitized data

    // ---- weights: w = exp(lw); rate = sum w; p = w/rate  (steps {1,-1,-3,3,4,-4})
    float rate, p0, p1, p2, p3, p4, p5;
    {
        const float* lw = logw + row * NSTEPS;
        p0 = expf(lw[0]); p1 = expf(lw[1]); p2 = expf(lw[2]);
        p3 = expf(lw[3]); p4 = expf(lw[4]); p5 = expf(lw[5]);
        rate = ((p0 + p1) + (p2 + p3)) + (p4 + p5);
        const float inv = 1.0f / rate;
        p0 *= inv; p1 *= inv; p2 *= inv; p3 *= inv; p4 *= inv; p5 *= inv;
    }

    // ---- data load (2 cols/lane), sanitize, plogp = sum d*ln(d) over nonzero cols
    float plogp;
    {
        const float2 dv = *(const float2*)(data + row * NC + 2 * lane);
        const float d0 = (dv.x > 1e-8f) ? dv.x : 0.f;   // isclose(data,0) atol
        const float d1 = (dv.y > 1e-8f) ? dv.y : 0.f;
        *(float2*)(dsh + 2 * lane) = make_float2(d0, d1);
        float pl = 0.f;
        if (d0 > 0.f) pl += d0 * logf(d0);
        if (d1 > 0.f) pl += d1 * logf(d1);
        #pragma unroll
        for (int off = 1; off < 64; off <<= 1) pl += __shfl_xor(pl, off, 64);
        plogp = pl;
    }

    // ---- Poisson-weighted diffusion, all in registers (pmf by recurrence)
    float r0 = 0.f, r1 = 0.f, r2 = 0.f, r3 = 0.f;
    if (lane == 32) r0 = 1.0f;                 // center state 128 = 4*32+0
    float a0 = 0.f, a1 = 0.f, a2 = 0.f, a3 = 0.f;
    float sp = expf(-rate);                    // pmf(0)
    const float mL = (lane == 0)  ? 0.f : 1.f; // zero out-of-support neighbors
    const float mR = (lane == 63) ? 0.f : 1.f;
    #pragma unroll
    for (int n = 0; n < NITERS; ++n) {
        a0 += sp * r0; a1 += sp * r1; a2 += sp * r2; a3 += sp * r3;
        const float L0 = __shfl_up(r0, 1, 64) * mL;   // lane-1 states 4l-4..4l-1
        const float L1 = __shfl_up(r1, 1, 64) * mL;
        const float L2 = __shfl_up(r2, 1, 64) * mL;
        const float L3 = __shfl_up(r3, 1, 64) * mL;
        const float R0 = __shfl_down(r0, 1, 64) * mR; // lane+1 states 4l+4..4l+7
        const float R1 = __shfl_down(r1, 1, 64) * mR;
        const float R2 = __shfl_down(r2, 1, 64) * mR;
        const float R3 = __shfl_down(r3, 1, 64) * mR;
        // new[t] = sum_i p[i]*cur[t-steps[i]] ; t = 4*lane + j
        const float n0 = p0*L3 + p1*r1 + p2*r3 + p3*L1 + p4*L0 + p5*R0;
        const float n1 = p0*r0 + p1*r2 + p2*R0 + p3*L2 + p4*L1 + p5*R1;
        const float n2 = p0*r1 + p1*r3 + p2*R1 + p3*L3 + p4*L2 + p5*R2;
        const float n3 = p0*r2 + p1*R0 + p2*R2 + p3*r0 + p4*L3 + p5*R3;
        r0 = n0; r1 = n1; r2 = n2; r3 = n3;
        sp = sp * rate * (1.0f / (float)(n + 1));     // folds: n is unroll-const
    }

    // ---- licd = log2(raw acc)  (normalizations cancel inside q = acc/Z)
    *(float4*)(licd + 4 * lane) = make_float4(log2f(a0), log2f(a1), log2f(a2), log2f(a3));

    // ---- inclusive prefix sum P of raw acc (in-lane serial + wave scan)
    const float s0 = a0, s1 = s0 + a1, s2 = s1 + a2, s3 = s2 + a3;
    float t = s3;
    #pragma unroll
    for (int off = 1; off < 64; off <<= 1) {
        const float u = __shfl_up(t, off, 64);
        if (lane >= off) t += u;
    }
    const float base = t - s3;
    *(float4*)(P + 4 * lane) = make_float4(base + s0, base + s1, base + s2, base + s3);

    // ---- matching: shifts sA = lane, sB = lane+64 share one licd read stream
    // log q = licd[s+c] - log2(Z_s); per-term clamp at log2(1e-38) == reference.
    const int sA = lane, sB = lane + 64;
    const float zA = log2f(P[sA + 127] - (sA ? P[sA - 1] : 0.f));
    const float zB = log2f(P[sB + 127] - P[sB - 1]);
    float accA = 0.f, accB = 0.f;
    const float* lc = licd + lane;
    #pragma unroll 8
    for (int idx = 0; idx < 64; ++idx)           // sA cols 0..63
        accA += dsh[idx] * fmaxf(lc[idx] - zA, CL2);
    #pragma unroll 8
    for (int idx = 64; idx < 128; ++idx) {       // sA cols 64..127, sB cols 0..63
        const float v = lc[idx];
        accA += dsh[idx]      * fmaxf(v - zA, CL2);
        accB += dsh[idx - 64] * fmaxf(v - zB, CL2);
    }
    #pragma unroll 8
    for (int idx = 128; idx < 192; ++idx)        // sB cols 64..127
        accB += dsh[idx - 64] * fmaxf(lc[idx] - zB, CL2);
    float best = fminf(plogp - LN2 * accA, plogp - LN2 * accB);

    // ---- shift 128: distributed over all 64 lanes (2 cols each) + reduce
    {
        const float z = log2f(P[255] - P[127]);
        float part = dsh[2 * lane]     * fmaxf(licd[128 + 2 * lane] - z, CL2)
                   + dsh[2 * lane + 1] * fmaxf(licd[129 + 2 * lane] - z, CL2);
        #pragma unroll
        for (int off = 1; off < 64; off <<= 1) part += __shfl_xor(part, off, 64);
        best = fminf(best, plogp - LN2 * part);
    }

    // ---- wave min, lane 0 stores
    #pragma unroll
    for (int off = 1; off < 64; off <<= 1) best = fminf(best, __shfl_xor(best, off, 64));
    if (lane == 0) out[row] = best;
}

extern "C" void kernel_launch(void* const* d_in, const int* in_sizes, int n_in,
                              void* d_out, int out_size, void* d_ws, size_t ws_size,
                              hipStream_t stream)
{
    const float* data = (const float*)d_in[0];   // [n, 128] f32
    const float* logw = (const float*)d_in[1];   // [n, 6]   f32
    float* out = (float*)d_out;                  // [n]      f32
    const int n_rows = in_sizes[0] / NC;
    const int blocks = (n_rows + RPB - 1) / RPB;
    tonal_diffusion_kernel<<<blocks, 256, 0, stream>>>(data, logw, out, n_rows);
}

// Round 8
// 75.273 us; speedup vs baseline: 1.2580x; 1.0334x over previous
//
#include <hip/hip_runtime.h>
#include <math.h>

#define NC      128   // data columns
#define NSTATE  256   // n_dist_support
#define NITERS  33
#define NSTEPS  6
#define RPB     4     // rows (= independent waves) per block
#define CL2     (-126.22347f)          // log2(1e-38): reference underflow clamp
#define LN2     (0.6931471805599453f)

#define DPP_WAVE_SHL1 0x130   // lane l <- lane l+1 (bound_ctrl: lane63 -> 0)
#define DPP_WAVE_SHR1 0x138   // lane l <- lane l-1 (bound_ctrl: lane0  -> 0)

__device__ __forceinline__ float dpp_shr1(float x) {   // value from lane-1, 0 at lane 0
    return __int_as_float(__builtin_amdgcn_update_dpp(
        0, __float_as_int(x), DPP_WAVE_SHR1, 0xf, 0xf, true));
}
__device__ __forceinline__ float dpp_shl1(float x) {   // value from lane+1, 0 at lane 63
    return __int_as_float(__builtin_amdgcn_update_dpp(
        0, __float_as_int(x), DPP_WAVE_SHL1, 0xf, 0xf, true));
}

// One WAVE per data row; 4 independent waves per block; no __syncthreads anywhere.
// Diffusion states in registers (state 4*lane+j), neighbor exchange via DPP (VALU).
__global__ __launch_bounds__(256)
void tonal_diffusion_kernel(const float* __restrict__ data,
                            const float* __restrict__ logw,
                            float* __restrict__ out, int n_rows)
{
    const int wid  = threadIdx.x >> 6;
    const int lane = threadIdx.x & 63;
    const int row  = blockIdx.x * RPB + wid;
    if (row >= n_rows) return;
    const int urow = __builtin_amdgcn_readfirstlane(row);   // wave-uniform row

    // licdR[p][k] = log2(accRaw[k+p]) : 4 rotated copies -> aligned b128 reads
    __shared__ __align__(16) float licdR_s[RPB][4][NSTATE];
    __shared__ __align__(16) float P_s    [RPB][NSTATE];    // inclusive prefix of acc
    float (* __restrict__ licdR)[NSTATE] = licdR_s[wid];
    float * __restrict__ P               = P_s[wid];

    const float* __restrict__ drow = data + (size_t)urow * NC;  // uniform pointer

    // ---- weights: w = exp(lw); rate = sum w; p = w/rate  (steps {1,-1,-3,3,4,-4})
    float rate, p0, p1, p2, p3, p4, p5;
    {
        const float* lw = logw + urow * NSTEPS;
        p0 = expf(lw[0]); p1 = expf(lw[1]); p2 = expf(lw[2]);
        p3 = expf(lw[3]); p4 = expf(lw[4]); p5 = expf(lw[5]);
        rate = ((p0 + p1) + (p2 + p3)) + (p4 + p5);
        const float inv = 1.0f / rate;
        p0 *= inv; p1 *= inv; p2 *= inv; p3 *= inv; p4 *= inv; p5 *= inv;
    }

    // ---- per-lane data (cols 2*lane, 2*lane+1): plogp with zero-guard (raw kept)
    const float2 dl = *(const float2*)(drow + 2 * lane);
    float plogp;
    {
        float pl = 0.f;
        if (dl.x > 1e-8f) pl += dl.x * logf(dl.x);   // isclose(data,0) excluded
        if (dl.y > 1e-8f) pl += dl.y * logf(dl.y);
        #pragma unroll
        for (int off = 1; off < 64; off <<= 1) pl += __shfl_xor(pl, off, 64);
        plogp = pl;
    }

    // ---- Poisson-weighted diffusion, registers only; neighbors via DPP (no DS)
    float r0 = 0.f, r1 = 0.f, r2 = 0.f, r3 = 0.f;
    if (lane == 32) r0 = 1.0f;                 // center state 128 = 4*32+0
    float a0 = 0.f, a1 = 0.f, a2 = 0.f, a3 = 0.f;
    float sp = expf(-rate);                    // Poisson pmf(0)
    #pragma unroll
    for (int n = 0; n < NITERS; ++n) {
        a0 += sp * r0; a1 += sp * r1; a2 += sp * r2; a3 += sp * r3;
        const float L0 = dpp_shr1(r0), L1 = dpp_shr1(r1),
                    L2 = dpp_shr1(r2), L3 = dpp_shr1(r3);   // lane-1 (0 at edge)
        const float R0 = dpp_shl1(r0), R1 = dpp_shl1(r1),
                    R2 = dpp_shl1(r2), R3 = dpp_shl1(r3);   // lane+1 (0 at edge)
        // new[t] = sum_i p[i]*cur[t-steps[i]] ; t = 4*lane + j
        const float n0 = p0*L3 + p1*r1 + p2*r3 + p3*L1 + p4*L0 + p5*R0;
        const float n1 = p0*r0 + p1*r2 + p2*R0 + p3*L2 + p4*L1 + p5*R1;
        const float n2 = p0*r1 + p1*r3 + p2*R1 + p3*L3 + p4*L2 + p5*R2;
        const float n3 = p0*r2 + p1*R0 + p2*R2 + p3*r0 + p4*L3 + p5*R3;
        r0 = n0; r1 = n1; r2 = n2; r3 = n3;
        sp = sp * rate * (1.0f / (float)(n + 1));     // folds under full unroll
    }

    // ---- licd = log2(raw acc); build 4 rotated copies with aligned b128 stores
    {
        const float l0 = log2f(a0), l1 = log2f(a1), l2 = log2f(a2), l3 = log2f(a3);
        const float nl0 = dpp_shl1(l0), nl1 = dpp_shl1(l1), nl2 = dpp_shl1(l2);
        // copy p at [4l..4l+3] holds licd[4l+p .. 4l+3+p] (tail entries unused)
        *(float4*)&licdR[0][4 * lane] = make_float4(l0, l1, l2, l3);
        *(float4*)&licdR[1][4 * lane] = make_float4(l1, l2, l3, nl0);
        *(float4*)&licdR[2][4 * lane] = make_float4(l2, l3, nl0, nl1);
        *(float4*)&licdR[3][4 * lane] = make_float4(l3, nl0, nl1, nl2);
    }

    // ---- inclusive prefix sum P of raw acc (in-lane serial + wave scan)
    {
        const float s0 = a0, s1 = s0 + a1, s2 = s1 + a2, s3 = s2 + a3;
        float t = s3;
        #pragma unroll
        for (int off = 1; off < 64; off <<= 1) {
            const float u = __shfl_up(t, off, 64);
            if (lane >= off) t += u;
        }
        const float base = t - s3;
        *(float4*)&P[4 * lane] = make_float4(base + s0, base + s1, base + s2, base + s3);
    }

    // ---- matching: shifts sA=lane, sB=lane+64 share one aligned licd float4 stream.
    // log q = licd[s+c] - log2(Z_s); per-term clamp at log2(1e-38) == reference.
    // d factor uses RAW data (uniform scalar loads): d<=1e-8 contributes <=1e-6 abs.
    const int phi = lane & 3;
    const float* __restrict__ lcp = &licdR[phi][lane - phi];   // 16B-aligned per lane
    const float zA = log2f(P[lane + 127] - (lane ? P[lane - 1] : 0.f));
    const float zB = log2f(P[lane + 191] - P[lane + 63]);
    float accA = 0.f, accB = 0.f;
    #pragma unroll 8
    for (int m = 0; m < 16; ++m) {             // sA cols 0..63
        const float4 v = *(const float4*)(lcp + 4 * m);
        const int c = 4 * m;
        accA += drow[c + 0] * fmaxf(v.x - zA, CL2);
        accA += drow[c + 1] * fmaxf(v.y - zA, CL2);
        accA += drow[c + 2] * fmaxf(v.z - zA, CL2);
        accA += drow[c + 3] * fmaxf(v.w - zA, CL2);
    }
    #pragma unroll 8
    for (int m = 16; m < 32; ++m) {            // sA cols 64..127 / sB cols 0..63
        const float4 v = *(const float4*)(lcp + 4 * m);
        const int c = 4 * m;
        accA += drow[c + 0] * fmaxf(v.x - zA, CL2);
        accA += drow[c + 1] * fmaxf(v.y - zA, CL2);
        accA += drow[c + 2] * fmaxf(v.z - zA, CL2);
        accA += drow[c + 3] * fmaxf(v.w - zA, CL2);
        accB += drow[c - 64 + 0] * fmaxf(v.x - zB, CL2);
        accB += drow[c - 64 + 1] * fmaxf(v.y - zB, CL2);
        accB += drow[c - 64 + 2] * fmaxf(v.z - zB, CL2);
        accB += drow[c - 64 + 3] * fmaxf(v.w - zB, CL2);
    }
    #pragma unroll 8
    for (int m = 32; m < 48; ++m) {            // sB cols 64..127
        const float4 v = *(const float4*)(lcp + 4 * m);
        const int c = 4 * m - 64;
        accB += drow[c + 0] * fmaxf(v.x - zB, CL2);
        accB += drow[c + 1] * fmaxf(v.y - zB, CL2);
        accB += drow[c + 2] * fmaxf(v.z - zB, CL2);
        accB += drow[c + 3] * fmaxf(v.w - zB, CL2);
    }
    float best = fminf(plogp - LN2 * accA, plogp - LN2 * accB);

    // ---- shift 128: 2 cols/lane (raw local data) + wave reduce
    {
        const float z = log2f(P[255] - P[127]);
        const float2 lv = *(const float2*)(&licdR[0][128 + 2 * lane]);  // 8B aligned
        float part = dl.x * fmaxf(lv.x - z, CL2) + dl.y * fmaxf(lv.y - z, CL2);
        #pragma unroll
        for (int off = 1; off < 64; off <<= 1) part += __shfl_xor(part, off, 64);
        best = fminf(best, plogp - LN2 * part);
    }

    // ---- wave min, lane 0 stores
    #pragma unroll
    for (int off = 1; off < 64; off <<= 1) best = fminf(best, __shfl_xor(best, off, 64));
    if (lane == 0) out[row] = best;
}

extern "C" void kernel_launch(void* const* d_in, const int* in_sizes, int n_in,
                              void* d_out, int out_size, void* d_ws, size_t ws_size,
                              hipStream_t stream)
{
    const float* data = (const float*)d_in[0];   // [n, 128] f32
    const float* logw = (const float*)d_in[1];   // [n, 6]   f32
    float* out = (float*)d_out;                  // [n]      f32
    const int n_rows = in_sizes[0] / NC;
    const int blocks = (n_rows + RPB - 1) / RPB;
    tonal_diffusion_kernel<<<blocks, 256, 0, stream>>>(data, logw, out, n_rows);
}